// Round 9
// baseline (385.067 us; speedup 1.0000x reference)
//
#include <hip/hip_runtime.h>

static constexpr int NNODE = 100000;
static constexpr int NEDGE = 1600000;
static constexpr int EPOS  = 100000;
static constexpr int ENEG  = 500000;
static constexpr int F     = 128;
static constexpr int CLS   = 16;
static constexpr int NBKT  = 392;      // buckets of 256 nodes (dst >> 8); 392*256 = 100352
static constexpr int BCAP  = 4608;     // bucket capacity (mean 4096, +8 sigma)
static constexpr int TILE  = 2048;     // edges per k_bin block
static constexpr int NTB   = (NEDGE + TILE - 1) / TILE;   // 782
static constexpr int CASTB = NNODE * F / 4 / 256;         // 12500 cast blocks
static constexpr int NS    = 13;       // src slices of 8192 nodes (src >> 13)
static constexpr int AGB   = 1568;     // k_agg blocks: 1568 * 64 rows = 100352

using bf16x8 = __attribute__((ext_vector_type(8))) short;
using f32x4  = __attribute__((ext_vector_type(4))) float;

// ---------------- bf16 helpers ----------------

__device__ __forceinline__ ushort f2b(float f) {           // f32 -> bf16 RNE
    unsigned u = __float_as_uint(f);
    unsigned r = u + 0x7fffu + ((u >> 16) & 1u);
    return (ushort)(r >> 16);
}
__device__ __forceinline__ float b2f(ushort h) {
    return __uint_as_float(((unsigned)h) << 16);
}

// cast X (blocks 0..CASTB) + repack weights (blocks CASTB..CASTB+272)
__global__ void k_prep(const float* __restrict__ x, ushort* __restrict__ xb,
                       const float* __restrict__ W1s, const float* __restrict__ W1n,
                       const float* __restrict__ W2s, const float* __restrict__ W2n,
                       const float* __restrict__ W3s, const float* __restrict__ W3n,
                       ushort* __restrict__ o1s, ushort* __restrict__ o1n,
                       ushort* __restrict__ o2s, ushort* __restrict__ o2n,
                       ushort* __restrict__ o3s, ushort* __restrict__ o3n) {
    const int t = threadIdx.x;
    if (blockIdx.x < CASTB) {
        const int i = blockIdx.x * 256 + t;
        float4 v = ((const float4*)x)[i];
        ushort4 o; o.x = f2b(v.x); o.y = f2b(v.y); o.z = f2b(v.z); o.w = f2b(v.w);
        ((ushort4*)xb)[i] = o;
        return;
    }
    const int b = blockIdx.x - CASTB;
    const float* src; ushort* dst; int C; int idx;
    if      (b < 64)  { src = W1s; dst = o1s; C = 128; idx = b * 256 + t; }
    else if (b < 128) { src = W1n; dst = o1n; C = 128; idx = (b - 64) * 256 + t; }
    else if (b < 192) { src = W2s; dst = o2s; C = 128; idx = (b - 128) * 256 + t; }
    else if (b < 256) { src = W2n; dst = o2n; C = 128; idx = (b - 192) * 256 + t; }
    else if (b < 264) { src = W3s; dst = o3s; C = 16;  idx = (b - 256) * 256 + t; }
    else              { src = W3n; dst = o3n; C = 16;  idx = (b - 264) * 256 + t; }
    const int k = idx / C, c = idx % C;
    dst[(k >> 3) * C * 8 + c * 8 + (k & 7)] = f2b(src[idx]);
}

// ---------------- CSR build: bucket binning (phase 1) ----------------

__global__ __launch_bounds__(256) void k_bin(
    const int* __restrict__ src, const int* __restrict__ dst,
    uint* __restrict__ bins, int* __restrict__ gcount) {
    __shared__ int  hist[NBKT];
    __shared__ int  lofs[NBKT];
    __shared__ int  gbase[NBKT];
    __shared__ int  run[NBKT];
    __shared__ int  tmp[256];
    __shared__ uint stage[TILE];
    const int tid = threadIdx.x;
    const int e0  = blockIdx.x * TILE;

    for (int i = tid; i < NBKT; i += 256) hist[i] = 0;
    __syncthreads();
    #pragma unroll
    for (int j = 0; j < TILE / 256; ++j) {
        const int e = e0 + j * 256 + tid;
        if (e < NEDGE) atomicAdd(&hist[dst[e] >> 8], 1);
    }
    __syncthreads();
    const int i0 = 2 * tid, i1 = 2 * tid + 1;
    const int a0 = (i0 < NBKT) ? hist[i0] : 0;
    const int a1 = (i1 < NBKT) ? hist[i1] : 0;
    tmp[tid] = a0 + a1;
    __syncthreads();
    for (int off = 1; off < 256; off <<= 1) {
        int y = (tid >= off) ? tmp[tid - off] : 0;
        __syncthreads();
        tmp[tid] += y;
        __syncthreads();
    }
    const int pbase = tid ? tmp[tid - 1] : 0;
    if (i0 < NBKT) { lofs[i0] = pbase;      run[i0] = pbase; }
    if (i1 < NBKT) { lofs[i1] = pbase + a0; run[i1] = pbase + a0; }
    __syncthreads();
    for (int i = tid; i < NBKT; i += 256)
        gbase[i] = (hist[i] > 0) ? atomicAdd(&gcount[i], hist[i]) : 0;
    __syncthreads();
    #pragma unroll
    for (int j = 0; j < TILE / 256; ++j) {
        const int e = e0 + j * 256 + tid;
        if (e < NEDGE) {
            const int d = dst[e];
            const int b = d >> 8;
            const int r = atomicAdd(&run[b], 1);
            stage[r] = (uint)(src[e] | ((d & 255) << 17));
        }
    }
    __syncthreads();
    const int total = lofs[NBKT - 1] + hist[NBKT - 1];
    for (int i = tid; i < total; i += 256) {
        int lo = 0, hi = NBKT - 1;                  // largest b with lofs[b] <= i
        while (lo < hi) {
            const int mid = (lo + hi + 1) >> 1;
            if (lofs[mid] <= i) lo = mid; else hi = mid - 1;
        }
        bins[(size_t)lo * BCAP + gbase[lo] + (i - lofs[lo])] = stage[i];
    }
}

// exclusive scan of gcount[NBKT] -> ebase[NBKT]
__global__ void k_bscan(const int* __restrict__ gcount, int* __restrict__ ebase) {
    __shared__ int s[256];
    const int t = threadIdx.x;
    const int i0 = 2 * t, i1 = 2 * t + 1;
    const int a0 = (i0 < NBKT) ? gcount[i0] : 0;
    const int a1 = (i1 < NBKT) ? gcount[i1] : 0;
    s[t] = a0 + a1;
    __syncthreads();
    for (int off = 1; off < 256; off <<= 1) {
        int y = (t >= off) ? s[t - off] : 0;
        __syncthreads();
        s[t] += y;
        __syncthreads();
    }
    const int pbase = t ? s[t - 1] : 0;
    if (i0 < NBKT) ebase[i0] = pbase;
    if (i1 < NBKT) ebase[i1] = pbase + a0;
}

// ---------------- CSR build phase 2: sort by (node, src-slice) ----------------
// Writes col (sorted), rp (row starts, +sentinel), rps2[node*16+s] slice starts
// (entry 13 == row end since slices 13..15 are empty).

__global__ __launch_bounds__(256) void k_build(
    const uint* __restrict__ bins, const int* __restrict__ gcount,
    const int* __restrict__ ebase, int* __restrict__ rp,
    int* __restrict__ rps2, int* __restrict__ col) {
    __shared__ int cnt2[4096];     // key = dlow*16 + slice
    __shared__ int tmp[256];
    const int tid = threadIdx.x;
    const int b   = blockIdx.x;
    const int nbase = b * 256;
    const int cnt   = gcount[b];
    const int eb    = ebase[b];
    const uint* mybins = bins + (size_t)b * BCAP;

    for (int i = tid; i < 4096; i += 256) cnt2[i] = 0;
    __syncthreads();
    for (int i = tid; i < cnt; i += 256) {
        const uint v = mybins[i];
        const int dlow = (v >> 17) & 255;
        const int s    = (v & 0x1FFFF) >> 13;
        atomicAdd(&cnt2[dlow * 16 + s], 1);
    }
    __syncthreads();
    // row (=dlow=tid) sums, block scan, then exclusive within row
    int lc[16];
    int rsum = 0;
    #pragma unroll
    for (int k = 0; k < 16; ++k) { lc[k] = cnt2[tid * 16 + k]; rsum += lc[k]; }
    tmp[tid] = rsum;
    __syncthreads();
    for (int off = 1; off < 256; off <<= 1) {
        int y = (tid >= off) ? tmp[tid - off] : 0;
        __syncthreads();
        tmp[tid] += y;
        __syncthreads();
    }
    const int rbase = tid ? tmp[tid - 1] : 0;
    int run = rbase;
    #pragma unroll
    for (int k = 0; k < 16; ++k) { cnt2[tid * 16 + k] = run; run += lc[k]; }
    __syncthreads();
    // write rp / rps2
    rp[nbase + tid] = eb + rbase;
    {
        int4* dst = (int4*)(rps2 + (size_t)(nbase + tid) * 16);
        #pragma unroll
        for (int q = 0; q < 4; ++q) {
            int4 v;
            v.x = eb + cnt2[tid * 16 + q * 4 + 0];
            v.y = eb + cnt2[tid * 16 + q * 4 + 1];
            v.z = eb + cnt2[tid * 16 + q * 4 + 2];
            v.w = eb + cnt2[tid * 16 + q * 4 + 3];
            dst[q] = v;
        }
    }
    __syncthreads();
    for (int i = tid; i < cnt; i += 256) {
        const uint v = mybins[i];
        const int dlow = (v >> 17) & 255;
        const int s    = (v & 0x1FFFF) >> 13;
        const int p = atomicAdd(&cnt2[dlow * 16 + s], 1);
        col[eb + p] = (int)(v & 0x1FFFF);
    }
    if (b == NBKT - 1 && tid == 0) rp[NBKT * 256] = eb + cnt;   // sentinel
}

// ---------------- aggregation: slice-synchronized persistent grid ----------------
// 1568 blocks x 64 rows; all blocks sweep src-slices in the same order so the
// instantaneous gather working set (~2 MB/slice) stays L2-resident per XCD.

__global__ __launch_bounds__(256) void k_agg(
    const ushort* __restrict__ hin, const int* __restrict__ rps2,
    const int* __restrict__ col, ushort* __restrict__ agg) {
    const int tid = threadIdx.x;
    const int g   = tid >> 4;          // 16 thread-groups
    const int l16 = tid & 15;
    const int grp0 = blockIdx.x * 4;   // 4 row-groups of 16 rows

    float acc[4][8];
    #pragma unroll
    for (int gi = 0; gi < 4; ++gi)
        #pragma unroll
        for (int j = 0; j < 8; ++j) acc[gi][j] = 0.f;

    for (int s = 0; s < NS; ++s) {
        #pragma unroll
        for (int gi = 0; gi < 4; ++gi) {
            const int r = (grp0 + gi) * 16 + g;
            const int2 bb = *(const int2*)(rps2 + (size_t)r * 16 + s);
            for (int p = bb.x; p < bb.y; ++p) {
                const bf16x8 a = *(const bf16x8*)(hin + (size_t)col[p] * F + l16 * 8);
                #pragma unroll
                for (int j = 0; j < 8; ++j) acc[gi][j] += b2f((ushort)a[j]);
            }
        }
    }

    #pragma unroll
    for (int gi = 0; gi < 4; ++gi) {
        const int r = (grp0 + gi) * 16 + g;
        if (r < NNODE) {
            const int d = rps2[(size_t)r * 16 + 13] - rps2[(size_t)r * 16];
            const float inv = d > 0 ? 1.0f / (float)d : 0.0f;
            bf16x8 o;
            #pragma unroll
            for (int j = 0; j < 8; ++j) o[j] = (short)f2b(acc[gi][j] * inv);
            *(bf16x8*)(agg + (size_t)r * F + l16 * 8) = o;
        }
    }
}

// width-16 aggregation for G3, RMW-adds mean into H3 (bf16). 2 lanes/row.
__global__ __launch_bounds__(256) void k_agg16(
    const ushort* __restrict__ G, const int* __restrict__ rp,
    const int* __restrict__ col, ushort* __restrict__ H3) {
    const int tid  = threadIdx.x;
    const int row  = blockIdx.x * 128 + (tid >> 1);
    const int half = tid & 1;
    if (row >= NNODE) return;
    const int p0 = rp[row];
    const int pe = rp[row + 1];
    const int d  = pe - p0;
    if (d == 0) return;
    float s0[8] = {0, 0, 0, 0, 0, 0, 0, 0};
    float s1[8] = {0, 0, 0, 0, 0, 0, 0, 0};
    int p = p0;
    for (; p + 2 <= pe; p += 2) {
        const int u0 = col[p];
        const int u1 = col[p + 1];
        const bf16x8 a = *(const bf16x8*)(G + (size_t)u0 * CLS + half * 8);
        const bf16x8 b = *(const bf16x8*)(G + (size_t)u1 * CLS + half * 8);
        #pragma unroll
        for (int j = 0; j < 8; ++j) s0[j] += b2f((ushort)a[j]);
        #pragma unroll
        for (int j = 0; j < 8; ++j) s1[j] += b2f((ushort)b[j]);
    }
    if (p < pe) {
        const bf16x8 a = *(const bf16x8*)(G + (size_t)col[p] * CLS + half * 8);
        #pragma unroll
        for (int j = 0; j < 8; ++j) s0[j] += b2f((ushort)a[j]);
    }
    const float inv = 1.0f / (float)d;
    ushort* dst = H3 + (size_t)row * CLS + half * 8;
    const bf16x8 cur = *(const bf16x8*)dst;
    bf16x8 o;
    #pragma unroll
    for (int j = 0; j < 8; ++j)
        o[j] = (short)f2b(b2f((ushort)cur[j]) + (s0[j] + s1[j]) * inv);
    *(bf16x8*)dst = o;
}

// ---------------- MFMA GEMM: out = relu(A1@Ws + A2@Wn + b), N=128 ----------------

__global__ __launch_bounds__(256) void k_gemm128(
    const ushort* __restrict__ A1, const ushort* __restrict__ A2,
    const ushort* __restrict__ Ws2, const ushort* __restrict__ Wn2,
    const float* __restrict__ bias, ushort* __restrict__ outb) {
    __shared__ ushort Wl[16384];                 // 32 KB: one weight matrix
    const int tid  = threadIdx.x;
    const int wv   = tid >> 6;
    const int lane = tid & 63;
    const int l16  = lane & 15;
    const int lk   = lane >> 4;
    const int rbase = blockIdx.x * 128 + wv * 32;

    f32x4 acc0[8], acc1[8];
    #pragma unroll
    for (int n = 0; n < 8; ++n) { acc0[n] = (f32x4){0,0,0,0}; acc1[n] = (f32x4){0,0,0,0}; }

    const int r0 = rbase + l16       < NNODE ? rbase + l16       : NNODE - 1;
    const int r1 = rbase + 16 + l16  < NNODE ? rbase + 16 + l16  : NNODE - 1;
    const size_t ra0 = (size_t)r0 * F + lk * 8;
    const size_t ra1 = (size_t)r1 * F + lk * 8;

    #pragma unroll
    for (int mat = 0; mat < 2; ++mat) {
        const ushort* W2 = mat ? Wn2 : Ws2;
        const ushort* A  = mat ? A2  : A1;
        __syncthreads();
        #pragma unroll
        for (int i = 0; i < 8; ++i)
            *(bf16x8*)&Wl[tid * 8 + i * 2048] = *(const bf16x8*)&W2[tid * 8 + i * 2048];
        __syncthreads();
        #pragma unroll
        for (int kb = 0; kb < 4; ++kb) {
            const bf16x8 a0 = *(const bf16x8*)(A + ra0 + kb * 32);
            const bf16x8 a1 = *(const bf16x8*)(A + ra1 + kb * 32);
            const int kg = kb * 4 + lk;
            #pragma unroll
            for (int n = 0; n < 8; ++n) {
                const bf16x8 b = *(const bf16x8*)&Wl[kg * 1024 + (n * 16 + l16) * 8];
                acc0[n] = __builtin_amdgcn_mfma_f32_16x16x32_bf16(a0, b, acc0[n], 0, 0, 0);
                acc1[n] = __builtin_amdgcn_mfma_f32_16x16x32_bf16(a1, b, acc1[n], 0, 0, 0);
            }
        }
    }

    #pragma unroll
    for (int n = 0; n < 8; ++n) {
        const int c = n * 16 + l16;
        const float bv = bias[c];
        #pragma unroll
        for (int j = 0; j < 4; ++j) {
            const int rr0 = rbase + lk * 4 + j;
            const int rr1 = rbase + 16 + lk * 4 + j;
            if (rr0 < NNODE) outb[(size_t)rr0 * F + c] = f2b(fmaxf(acc0[n][j] + bv, 0.f));
            if (rr1 < NNODE) outb[(size_t)rr1 * F + c] = f2b(fmaxf(acc1[n][j] + bv, 0.f));
        }
    }
}

// ---------------- dual MFMA GEMM: G3 = A@Wn3, H3 = A@Ws3 + b (both bf16), N=16 ----------------

__global__ __launch_bounds__(256) void k_gemm16d(
    const ushort* __restrict__ A, const ushort* __restrict__ Wn2,
    const ushort* __restrict__ Ws2, const float* __restrict__ bias,
    ushort* __restrict__ G3, ushort* __restrict__ H3) {
    __shared__ ushort Wn_l[2048];
    __shared__ ushort Ws_l[2048];
    const int tid  = threadIdx.x;
    const int wv   = tid >> 6;
    const int lane = tid & 63;
    const int l16  = lane & 15;
    const int lk   = lane >> 4;
    const int rbase = blockIdx.x * 256 + wv * 64;

    *(bf16x8*)&Wn_l[tid * 8] = *(const bf16x8*)&Wn2[tid * 8];
    *(bf16x8*)&Ws_l[tid * 8] = *(const bf16x8*)&Ws2[tid * 8];
    __syncthreads();

    f32x4 accN[4], accS[4];
    #pragma unroll
    for (int rt = 0; rt < 4; ++rt) { accN[rt] = (f32x4){0,0,0,0}; accS[rt] = (f32x4){0,0,0,0}; }

    #pragma unroll
    for (int kb = 0; kb < 4; ++kb) {
        const int kg = kb * 4 + lk;
        const bf16x8 bn = *(const bf16x8*)&Wn_l[kg * 128 + l16 * 8];
        const bf16x8 bs = *(const bf16x8*)&Ws_l[kg * 128 + l16 * 8];
        #pragma unroll
        for (int rt = 0; rt < 4; ++rt) {
            int row = rbase + rt * 16 + l16;
            if (row >= NNODE) row = NNODE - 1;
            const bf16x8 a = *(const bf16x8*)(A + (size_t)row * F + kb * 32 + lk * 8);
            accN[rt] = __builtin_amdgcn_mfma_f32_16x16x32_bf16(a, bn, accN[rt], 0, 0, 0);
            accS[rt] = __builtin_amdgcn_mfma_f32_16x16x32_bf16(a, bs, accS[rt], 0, 0, 0);
        }
    }

    const float bv = bias[l16];
    #pragma unroll
    for (int rt = 0; rt < 4; ++rt) {
        #pragma unroll
        for (int j = 0; j < 4; ++j) {
            const int rr = rbase + rt * 16 + lk * 4 + j;
            if (rr < NNODE) {
                G3[(size_t)rr * CLS + l16] = f2b(accN[rt][j]);
                H3[(size_t)rr * CLS + l16] = f2b(accS[rt][j] + bv);
            }
        }
    }
}

// ---------------- edge scoring (bf16 H3) ----------------

__global__ void k_score(const ushort* __restrict__ H3,
                        const int* __restrict__ pu, const int* __restrict__ pv,
                        const int* __restrict__ nu, const int* __restrict__ nv,
                        float* __restrict__ out) {
    int i = blockIdx.x * 256 + threadIdx.x;
    if (i >= EPOS + ENEG) return;
    int u, v, o;
    if (i < EPOS) { u = pu[i]; v = pv[i]; o = i; }
    else { int j = i - EPOS; u = nu[j]; v = nv[j]; o = EPOS + j; }
    const bf16x8 a0 = *(const bf16x8*)(H3 + (size_t)u * CLS);
    const bf16x8 a1 = *(const bf16x8*)(H3 + (size_t)u * CLS + 8);
    const bf16x8 b0 = *(const bf16x8*)(H3 + (size_t)v * CLS);
    const bf16x8 b1 = *(const bf16x8*)(H3 + (size_t)v * CLS + 8);
    float s = 0.f;
    #pragma unroll
    for (int r = 0; r < 8; ++r) s += b2f((ushort)a0[r]) * b2f((ushort)b0[r]);
    #pragma unroll
    for (int r = 0; r < 8; ++r) s += b2f((ushort)a1[r]) * b2f((ushort)b1[r]);
    out[o] = s;
}

// ---------------- launch ----------------

extern "C" void kernel_launch(void* const* d_in, const int* in_sizes, int n_in,
                              void* d_out, int out_size, void* d_ws, size_t ws_size,
                              hipStream_t stream) {
    const float* x     = (const float*)d_in[0];
    const int*   src   = (const int*)d_in[1];
    const int*   dst   = (const int*)d_in[2];
    const int*   pos_u = (const int*)d_in[3];
    const int*   pos_v = (const int*)d_in[4];
    const int*   neg_u = (const int*)d_in[5];
    const int*   neg_v = (const int*)d_in[6];
    const float* W1s = (const float*)d_in[7];
    const float* W1n = (const float*)d_in[8];
    const float* b1  = (const float*)d_in[9];
    const float* W2s = (const float*)d_in[10];
    const float* W2n = (const float*)d_in[11];
    const float* b2  = (const float*)d_in[12];
    const float* W3s = (const float*)d_in[13];
    const float* W3n = (const float*)d_in[14];
    const float* b3  = (const float*)d_in[15];
    float* out = (float*)d_out;

    char* ws = (char*)d_ws;
    size_t off = 0;
    int* rp     = (int*)(ws + off); off += (size_t)(NBKT * 256 + 256) * 4;
    int* gcount = (int*)(ws + off); off += 512 * 4;
    int* ebase  = (int*)(ws + off); off += 512 * 4;
    off = (off + 255) & ~(size_t)255;
    int* rps2   = (int*)(ws + off); off += (size_t)NBKT * 256 * 16 * 4;
    off = (off + 255) & ~(size_t)255;
    uint* bins  = (uint*)(ws + off); off += (size_t)NBKT * BCAP * 4;
    int*  col   = (int*)(ws + off);  off += (size_t)NEDGE * 4;
    off = (off + 255) & ~(size_t)255;
    ushort* Xb   = (ushort*)(ws + off); off += (size_t)NNODE * F * 2;
    off = (off + 255) & ~(size_t)255;
    ushort* H1   = (ushort*)(ws + off); off += (size_t)NNODE * F * 2;
    off = (off + 255) & ~(size_t)255;
    ushort* H2   = (ushort*)(ws + off); off += (size_t)NNODE * F * 2;
    off = (off + 255) & ~(size_t)255;
    ushort* Agg  = (ushort*)(ws + off); off += (size_t)NNODE * F * 2;
    off = (off + 255) & ~(size_t)255;
    ushort* G3   = (ushort*)(ws + off); off += (size_t)NNODE * CLS * 2;
    off = (off + 255) & ~(size_t)255;
    ushort* H3   = (ushort*)(ws + off); off += (size_t)NNODE * CLS * 2;
    off = (off + 255) & ~(size_t)255;
    ushort* Wb1s = (ushort*)(ws + off); off += 16384 * 2;
    ushort* Wb1n = (ushort*)(ws + off); off += 16384 * 2;
    ushort* Wb2s = (ushort*)(ws + off); off += 16384 * 2;
    ushort* Wb2n = (ushort*)(ws + off); off += 16384 * 2;
    ushort* Wb3s = (ushort*)(ws + off); off += 2048 * 2;
    ushort* Wb3n = (ushort*)(ws + off); off += 2048 * 2;

    hipMemsetAsync(gcount, 0, 512 * 4, stream);

    k_prep<<<CASTB + 272, 256, 0, stream>>>(x, Xb, W1s, W1n, W2s, W2n, W3s, W3n,
                                            Wb1s, Wb1n, Wb2s, Wb2n, Wb3s, Wb3n);

    k_bin<<<NTB, 256, 0, stream>>>(src, dst, bins, gcount);
    k_bscan<<<1, 256, 0, stream>>>(gcount, ebase);
    k_build<<<NBKT, 256, 0, stream>>>(bins, gcount, ebase, rp, rps2, col);

    k_agg<<<AGB, 256, 0, stream>>>(Xb, rps2, col, Agg);
    k_gemm128<<<(NNODE + 127) / 128, 256, 0, stream>>>(Xb, Agg, Wb1s, Wb1n, b1, H1);

    k_agg<<<AGB, 256, 0, stream>>>(H1, rps2, col, Agg);
    k_gemm128<<<(NNODE + 127) / 128, 256, 0, stream>>>(H1, Agg, Wb2s, Wb2n, b2, H2);

    k_gemm16d<<<(NNODE + 255) / 256, 256, 0, stream>>>(H2, Wb3n, Wb3s, b3, G3, H3);
    k_agg16<<<(NNODE + 127) / 128, 256, 0, stream>>>(G3, rp, col, H3);

    k_score<<<(EPOS + ENEG + 255) / 256, 256, 0, stream>>>(H3, pos_u, pos_v,
                                                           neg_u, neg_v, out);
}

// Round 10
// 277.277 us; speedup vs baseline: 1.3887x; 1.3887x over previous
//
#include <hip/hip_runtime.h>

static constexpr int NNODE = 100000;
static constexpr int NEDGE = 1600000;
static constexpr int EPOS  = 100000;
static constexpr int ENEG  = 500000;
static constexpr int F     = 128;
static constexpr int CLS   = 16;
static constexpr int NBKT  = 392;      // buckets of 256 nodes (dst >> 8); 392*256 = 100352
static constexpr int BCAP  = 4608;     // bucket capacity (mean 4096, +8 sigma)
static constexpr int TILE  = 2048;     // edges per k_bin block
static constexpr int NTB   = (NEDGE + TILE - 1) / TILE;   // 782
static constexpr int CASTB = NNODE * F / 4 / 256;         // 12500 cast blocks

using bf16x8 = __attribute__((ext_vector_type(8))) short;
using f32x4  = __attribute__((ext_vector_type(4))) float;

// ---------------- bf16 helpers ----------------

__device__ __forceinline__ ushort f2b(float f) {           // f32 -> bf16 RNE
    unsigned u = __float_as_uint(f);
    unsigned r = u + 0x7fffu + ((u >> 16) & 1u);
    return (ushort)(r >> 16);
}
__device__ __forceinline__ float b2f(ushort h) {
    return __uint_as_float(((unsigned)h) << 16);
}

// cast X (blocks 0..CASTB) + repack weights (blocks CASTB..CASTB+272)
__global__ void k_prep(const float* __restrict__ x, ushort* __restrict__ xb,
                       const float* __restrict__ W1s, const float* __restrict__ W1n,
                       const float* __restrict__ W2s, const float* __restrict__ W2n,
                       const float* __restrict__ W3s, const float* __restrict__ W3n,
                       ushort* __restrict__ o1s, ushort* __restrict__ o1n,
                       ushort* __restrict__ o2s, ushort* __restrict__ o2n,
                       ushort* __restrict__ o3s, ushort* __restrict__ o3n) {
    const int t = threadIdx.x;
    if (blockIdx.x < CASTB) {
        const int i = blockIdx.x * 256 + t;
        float4 v = ((const float4*)x)[i];
        ushort4 o; o.x = f2b(v.x); o.y = f2b(v.y); o.z = f2b(v.z); o.w = f2b(v.w);
        ((ushort4*)xb)[i] = o;
        return;
    }
    const int b = blockIdx.x - CASTB;
    const float* src; ushort* dst; int C; int idx;
    if      (b < 64)  { src = W1s; dst = o1s; C = 128; idx = b * 256 + t; }
    else if (b < 128) { src = W1n; dst = o1n; C = 128; idx = (b - 64) * 256 + t; }
    else if (b < 192) { src = W2s; dst = o2s; C = 128; idx = (b - 128) * 256 + t; }
    else if (b < 256) { src = W2n; dst = o2n; C = 128; idx = (b - 192) * 256 + t; }
    else if (b < 264) { src = W3s; dst = o3s; C = 16;  idx = (b - 256) * 256 + t; }
    else              { src = W3n; dst = o3n; C = 16;  idx = (b - 264) * 256 + t; }
    const int k = idx / C, c = idx % C;
    dst[(k >> 3) * C * 8 + c * 8 + (k & 7)] = f2b(src[idx]);
}

// ---------------- CSR build: bucket binning (phase 1) ----------------

__global__ __launch_bounds__(256) void k_bin(
    const int* __restrict__ src, const int* __restrict__ dst,
    uint* __restrict__ bins, int* __restrict__ gcount) {
    __shared__ int  hist[NBKT];
    __shared__ int  lofs[NBKT];
    __shared__ int  gbase[NBKT];
    __shared__ int  run[NBKT];
    __shared__ int  tmp[256];
    __shared__ uint stage[TILE];
    const int tid = threadIdx.x;
    const int e0  = blockIdx.x * TILE;

    for (int i = tid; i < NBKT; i += 256) hist[i] = 0;
    __syncthreads();
    #pragma unroll
    for (int j = 0; j < TILE / 256; ++j) {
        const int e = e0 + j * 256 + tid;
        if (e < NEDGE) atomicAdd(&hist[dst[e] >> 8], 1);
    }
    __syncthreads();
    const int i0 = 2 * tid, i1 = 2 * tid + 1;
    const int a0 = (i0 < NBKT) ? hist[i0] : 0;
    const int a1 = (i1 < NBKT) ? hist[i1] : 0;
    tmp[tid] = a0 + a1;
    __syncthreads();
    for (int off = 1; off < 256; off <<= 1) {
        int y = (tid >= off) ? tmp[tid - off] : 0;
        __syncthreads();
        tmp[tid] += y;
        __syncthreads();
    }
    const int pbase = tid ? tmp[tid - 1] : 0;
    if (i0 < NBKT) { lofs[i0] = pbase;      run[i0] = pbase; }
    if (i1 < NBKT) { lofs[i1] = pbase + a0; run[i1] = pbase + a0; }
    __syncthreads();
    for (int i = tid; i < NBKT; i += 256)
        gbase[i] = (hist[i] > 0) ? atomicAdd(&gcount[i], hist[i]) : 0;
    __syncthreads();
    #pragma unroll
    for (int j = 0; j < TILE / 256; ++j) {
        const int e = e0 + j * 256 + tid;
        if (e < NEDGE) {
            const int d = dst[e];
            const int b = d >> 8;
            const int r = atomicAdd(&run[b], 1);
            stage[r] = (uint)(src[e] | ((d & 255) << 17));
        }
    }
    __syncthreads();
    const int total = lofs[NBKT - 1] + hist[NBKT - 1];
    for (int i = tid; i < total; i += 256) {
        int lo = 0, hi = NBKT - 1;                  // largest b with lofs[b] <= i
        while (lo < hi) {
            const int mid = (lo + hi + 1) >> 1;
            if (lofs[mid] <= i) lo = mid; else hi = mid - 1;
        }
        bins[(size_t)lo * BCAP + gbase[lo] + (i - lofs[lo])] = stage[i];
    }
}

// exclusive scan of gcount[NBKT] -> ebase[NBKT]
__global__ void k_bscan(const int* __restrict__ gcount, int* __restrict__ ebase) {
    __shared__ int s[256];
    const int t = threadIdx.x;
    const int i0 = 2 * t, i1 = 2 * t + 1;
    const int a0 = (i0 < NBKT) ? gcount[i0] : 0;
    const int a1 = (i1 < NBKT) ? gcount[i1] : 0;
    s[t] = a0 + a1;
    __syncthreads();
    for (int off = 1; off < 256; off <<= 1) {
        int y = (t >= off) ? s[t - off] : 0;
        __syncthreads();
        s[t] += y;
        __syncthreads();
    }
    const int pbase = t ? s[t - 1] : 0;
    if (i0 < NBKT) ebase[i0] = pbase;
    if (i1 < NBKT) ebase[i1] = pbase + a0;
}

// ---------------- CSR build: per-bucket degree/scan/scatter (phase 2) ----------------

__global__ __launch_bounds__(256) void k_build(
    const uint* __restrict__ bins, const int* __restrict__ gcount,
    const int* __restrict__ ebase, int* __restrict__ rp, int* __restrict__ col) {
    __shared__ int ldeg[256];
    __shared__ int lrp[256];
    const int tid = threadIdx.x;
    const int b   = blockIdx.x;
    const int nbase = b * 256;
    const int cnt   = gcount[b];
    const int eb    = ebase[b];
    const uint* mybins = bins + (size_t)b * BCAP;

    ldeg[tid] = 0;
    __syncthreads();
    for (int i = tid; i < cnt; i += 256)
        atomicAdd(&ldeg[(mybins[i] >> 17) & 255], 1);
    __syncthreads();
    const int x = ldeg[tid];
    lrp[tid] = x;
    __syncthreads();
    for (int off = 1; off < 256; off <<= 1) {
        int y = (tid >= off) ? lrp[tid - off] : 0;
        __syncthreads();
        lrp[tid] += y;
        __syncthreads();
    }
    const int excl = lrp[tid] - x;
    rp[nbase + tid] = eb + excl;
    ldeg[tid] = excl;                 // running counters
    __syncthreads();
    for (int i = tid; i < cnt; i += 256) {
        const uint v = mybins[i];
        const int dlow = (v >> 17) & 255;
        const int p = atomicAdd(&ldeg[dlow], 1);
        col[eb + p] = (int)(v & 0x1FFFF);
    }
    if (b == NBKT - 1 && tid == 0) rp[NBKT * 256] = eb + cnt;   // sentinel
}

// ---------------- aggregation: mean of neighbor rows (bf16 -> bf16), width 128 ----------------
// 4-way unrolled, scalar col loads (round-6 best: 58.4 us, 3.52 TB/s).

__global__ __launch_bounds__(256) void k_agg(
    const ushort* __restrict__ hin, const int* __restrict__ rp,
    const int* __restrict__ col, ushort* __restrict__ agg) {
    const int tid = threadIdx.x;
    const int row = blockIdx.x * 16 + (tid >> 4);   // 16 rows/block, 16 lanes/row
    const int l16 = tid & 15;
    const int p0 = rp[row];
    const int pe = rp[row + 1];
    const int d  = pe - p0;
    float s0[8] = {0, 0, 0, 0, 0, 0, 0, 0};
    float s1[8] = {0, 0, 0, 0, 0, 0, 0, 0};
    float s2[8] = {0, 0, 0, 0, 0, 0, 0, 0};
    float s3[8] = {0, 0, 0, 0, 0, 0, 0, 0};
    int p = p0;
    for (; p + 4 <= pe; p += 4) {
        const int u0 = col[p];
        const int u1 = col[p + 1];
        const int u2 = col[p + 2];
        const int u3 = col[p + 3];
        const bf16x8 a = *(const bf16x8*)(hin + (size_t)u0 * F + l16 * 8);
        const bf16x8 b = *(const bf16x8*)(hin + (size_t)u1 * F + l16 * 8);
        const bf16x8 c = *(const bf16x8*)(hin + (size_t)u2 * F + l16 * 8);
        const bf16x8 e = *(const bf16x8*)(hin + (size_t)u3 * F + l16 * 8);
        #pragma unroll
        for (int j = 0; j < 8; ++j) s0[j] += b2f((ushort)a[j]);
        #pragma unroll
        for (int j = 0; j < 8; ++j) s1[j] += b2f((ushort)b[j]);
        #pragma unroll
        for (int j = 0; j < 8; ++j) s2[j] += b2f((ushort)c[j]);
        #pragma unroll
        for (int j = 0; j < 8; ++j) s3[j] += b2f((ushort)e[j]);
    }
    for (; p < pe; ++p) {
        const bf16x8 a = *(const bf16x8*)(hin + (size_t)col[p] * F + l16 * 8);
        #pragma unroll
        for (int j = 0; j < 8; ++j) s0[j] += b2f((ushort)a[j]);
    }
    const float inv = d > 0 ? 1.0f / (float)d : 0.0f;
    bf16x8 o;
    #pragma unroll
    for (int j = 0; j < 8; ++j)
        o[j] = (short)f2b(((s0[j] + s1[j]) + (s2[j] + s3[j])) * inv);
    *(bf16x8*)(agg + (size_t)row * F + l16 * 8) = o;
}

// width-16 aggregation for G3, RMW-adds mean into H3 (bf16). 2 lanes/row.
__global__ __launch_bounds__(256) void k_agg16(
    const ushort* __restrict__ G, const int* __restrict__ rp,
    const int* __restrict__ col, ushort* __restrict__ H3) {
    const int tid  = threadIdx.x;
    const int row  = blockIdx.x * 128 + (tid >> 1);
    const int half = tid & 1;
    if (row >= NNODE) return;
    const int p0 = rp[row];
    const int pe = rp[row + 1];
    const int d  = pe - p0;
    if (d == 0) return;
    float s0[8] = {0, 0, 0, 0, 0, 0, 0, 0};
    float s1[8] = {0, 0, 0, 0, 0, 0, 0, 0};
    float s2[8] = {0, 0, 0, 0, 0, 0, 0, 0};
    float s3[8] = {0, 0, 0, 0, 0, 0, 0, 0};
    int p = p0;
    for (; p + 4 <= pe; p += 4) {
        const int u0 = col[p];
        const int u1 = col[p + 1];
        const int u2 = col[p + 2];
        const int u3 = col[p + 3];
        const bf16x8 a = *(const bf16x8*)(G + (size_t)u0 * CLS + half * 8);
        const bf16x8 b = *(const bf16x8*)(G + (size_t)u1 * CLS + half * 8);
        const bf16x8 c = *(const bf16x8*)(G + (size_t)u2 * CLS + half * 8);
        const bf16x8 e = *(const bf16x8*)(G + (size_t)u3 * CLS + half * 8);
        #pragma unroll
        for (int j = 0; j < 8; ++j) s0[j] += b2f((ushort)a[j]);
        #pragma unroll
        for (int j = 0; j < 8; ++j) s1[j] += b2f((ushort)b[j]);
        #pragma unroll
        for (int j = 0; j < 8; ++j) s2[j] += b2f((ushort)c[j]);
        #pragma unroll
        for (int j = 0; j < 8; ++j) s3[j] += b2f((ushort)e[j]);
    }
    for (; p < pe; ++p) {
        const bf16x8 a = *(const bf16x8*)(G + (size_t)col[p] * CLS + half * 8);
        #pragma unroll
        for (int j = 0; j < 8; ++j) s0[j] += b2f((ushort)a[j]);
    }
    const float inv = 1.0f / (float)d;
    ushort* dst = H3 + (size_t)row * CLS + half * 8;
    const bf16x8 cur = *(const bf16x8*)dst;
    bf16x8 o;
    #pragma unroll
    for (int j = 0; j < 8; ++j)
        o[j] = (short)f2b(b2f((ushort)cur[j]) +
                          ((s0[j] + s1[j]) + (s2[j] + s3[j])) * inv);
    *(bf16x8*)dst = o;
}

// ---------------- MFMA GEMM: out = relu(A1@Ws + A2@Wn + b), N=128 ----------------

__global__ __launch_bounds__(256) void k_gemm128(
    const ushort* __restrict__ A1, const ushort* __restrict__ A2,
    const ushort* __restrict__ Ws2, const ushort* __restrict__ Wn2,
    const float* __restrict__ bias, ushort* __restrict__ outb) {
    __shared__ ushort Wl[16384];                 // 32 KB: one weight matrix
    const int tid  = threadIdx.x;
    const int wv   = tid >> 6;
    const int lane = tid & 63;
    const int l16  = lane & 15;
    const int lk   = lane >> 4;
    const int rbase = blockIdx.x * 128 + wv * 32;

    f32x4 acc0[8], acc1[8];
    #pragma unroll
    for (int n = 0; n < 8; ++n) { acc0[n] = (f32x4){0,0,0,0}; acc1[n] = (f32x4){0,0,0,0}; }

    const int r0 = rbase + l16       < NNODE ? rbase + l16       : NNODE - 1;
    const int r1 = rbase + 16 + l16  < NNODE ? rbase + 16 + l16  : NNODE - 1;
    const size_t ra0 = (size_t)r0 * F + lk * 8;
    const size_t ra1 = (size_t)r1 * F + lk * 8;

    #pragma unroll
    for (int mat = 0; mat < 2; ++mat) {
        const ushort* W2 = mat ? Wn2 : Ws2;
        const ushort* A  = mat ? A2  : A1;
        __syncthreads();
        #pragma unroll
        for (int i = 0; i < 8; ++i)
            *(bf16x8*)&Wl[tid * 8 + i * 2048] = *(const bf16x8*)&W2[tid * 8 + i * 2048];
        __syncthreads();
        #pragma unroll
        for (int kb = 0; kb < 4; ++kb) {
            const bf16x8 a0 = *(const bf16x8*)(A + ra0 + kb * 32);
            const bf16x8 a1 = *(const bf16x8*)(A + ra1 + kb * 32);
            const int kg = kb * 4 + lk;
            #pragma unroll
            for (int n = 0; n < 8; ++n) {
                const bf16x8 b = *(const bf16x8*)&Wl[kg * 1024 + (n * 16 + l16) * 8];
                acc0[n] = __builtin_amdgcn_mfma_f32_16x16x32_bf16(a0, b, acc0[n], 0, 0, 0);
                acc1[n] = __builtin_amdgcn_mfma_f32_16x16x32_bf16(a1, b, acc1[n], 0, 0, 0);
            }
        }
    }

    #pragma unroll
    for (int n = 0; n < 8; ++n) {
        const int c = n * 16 + l16;
        const float bv = bias[c];
        #pragma unroll
        for (int j = 0; j < 4; ++j) {
            const int rr0 = rbase + lk * 4 + j;
            const int rr1 = rbase + 16 + lk * 4 + j;
            if (rr0 < NNODE) outb[(size_t)rr0 * F + c] = f2b(fmaxf(acc0[n][j] + bv, 0.f));
            if (rr1 < NNODE) outb[(size_t)rr1 * F + c] = f2b(fmaxf(acc1[n][j] + bv, 0.f));
        }
    }
}

// ---------------- dual MFMA GEMM: G3 = A@Wn3, H3 = A@Ws3 + b (both bf16), N=16 ----------------

__global__ __launch_bounds__(256) void k_gemm16d(
    const ushort* __restrict__ A, const ushort* __restrict__ Wn2,
    const ushort* __restrict__ Ws2, const float* __restrict__ bias,
    ushort* __restrict__ G3, ushort* __restrict__ H3) {
    __shared__ ushort Wn_l[2048];
    __shared__ ushort Ws_l[2048];
    const int tid  = threadIdx.x;
    const int wv   = tid >> 6;
    const int lane = tid & 63;
    const int l16  = lane & 15;
    const int lk   = lane >> 4;
    const int rbase = blockIdx.x * 256 + wv * 64;

    *(bf16x8*)&Wn_l[tid * 8] = *(const bf16x8*)&Wn2[tid * 8];
    *(bf16x8*)&Ws_l[tid * 8] = *(const bf16x8*)&Ws2[tid * 8];
    __syncthreads();

    f32x4 accN[4], accS[4];
    #pragma unroll
    for (int rt = 0; rt < 4; ++rt) { accN[rt] = (f32x4){0,0,0,0}; accS[rt] = (f32x4){0,0,0,0}; }

    #pragma unroll
    for (int kb = 0; kb < 4; ++kb) {
        const int kg = kb * 4 + lk;
        const bf16x8 bn = *(const bf16x8*)&Wn_l[kg * 128 + l16 * 8];
        const bf16x8 bs = *(const bf16x8*)&Ws_l[kg * 128 + l16 * 8];
        #pragma unroll
        for (int rt = 0; rt < 4; ++rt) {
            int row = rbase + rt * 16 + l16;
            if (row >= NNODE) row = NNODE - 1;
            const bf16x8 a = *(const bf16x8*)(A + (size_t)row * F + kb * 32 + lk * 8);
            accN[rt] = __builtin_amdgcn_mfma_f32_16x16x32_bf16(a, bn, accN[rt], 0, 0, 0);
            accS[rt] = __builtin_amdgcn_mfma_f32_16x16x32_bf16(a, bs, accS[rt], 0, 0, 0);
        }
    }

    const float bv = bias[l16];
    #pragma unroll
    for (int rt = 0; rt < 4; ++rt) {
        #pragma unroll
        for (int j = 0; j < 4; ++j) {
            const int rr = rbase + rt * 16 + lk * 4 + j;
            if (rr < NNODE) {
                G3[(size_t)rr * CLS + l16] = f2b(accN[rt][j]);
                H3[(size_t)rr * CLS + l16] = f2b(accS[rt][j] + bv);
            }
        }
    }
}

// ---------------- edge scoring (bf16 H3) ----------------

__global__ void k_score(const ushort* __restrict__ H3,
                        const int* __restrict__ pu, const int* __restrict__ pv,
                        const int* __restrict__ nu, const int* __restrict__ nv,
                        float* __restrict__ out) {
    int i = blockIdx.x * 256 + threadIdx.x;
    if (i >= EPOS + ENEG) return;
    int u, v, o;
    if (i < EPOS) { u = pu[i]; v = pv[i]; o = i; }
    else { int j = i - EPOS; u = nu[j]; v = nv[j]; o = EPOS + j; }
    const bf16x8 a0 = *(const bf16x8*)(H3 + (size_t)u * CLS);
    const bf16x8 a1 = *(const bf16x8*)(H3 + (size_t)u * CLS + 8);
    const bf16x8 b0 = *(const bf16x8*)(H3 + (size_t)v * CLS);
    const bf16x8 b1 = *(const bf16x8*)(H3 + (size_t)v * CLS + 8);
    float s = 0.f;
    #pragma unroll
    for (int r = 0; r < 8; ++r) s += b2f((ushort)a0[r]) * b2f((ushort)b0[r]);
    #pragma unroll
    for (int r = 0; r < 8; ++r) s += b2f((ushort)a1[r]) * b2f((ushort)b1[r]);
    out[o] = s;
}

// ---------------- launch ----------------

extern "C" void kernel_launch(void* const* d_in, const int* in_sizes, int n_in,
                              void* d_out, int out_size, void* d_ws, size_t ws_size,
                              hipStream_t stream) {
    const float* x     = (const float*)d_in[0];
    const int*   src   = (const int*)d_in[1];
    const int*   dst   = (const int*)d_in[2];
    const int*   pos_u = (const int*)d_in[3];
    const int*   pos_v = (const int*)d_in[4];
    const int*   neg_u = (const int*)d_in[5];
    const int*   neg_v = (const int*)d_in[6];
    const float* W1s = (const float*)d_in[7];
    const float* W1n = (const float*)d_in[8];
    const float* b1  = (const float*)d_in[9];
    const float* W2s = (const float*)d_in[10];
    const float* W2n = (const float*)d_in[11];
    const float* b2  = (const float*)d_in[12];
    const float* W3s = (const float*)d_in[13];
    const float* W3n = (const float*)d_in[14];
    const float* b3  = (const float*)d_in[15];
    float* out = (float*)d_out;

    char* ws = (char*)d_ws;
    size_t off = 0;
    int* rp     = (int*)(ws + off); off += (size_t)(NBKT * 256 + 256) * 4;
    int* gcount = (int*)(ws + off); off += 512 * 4;
    int* ebase  = (int*)(ws + off); off += 512 * 4;
    off = (off + 255) & ~(size_t)255;
    uint* bins  = (uint*)(ws + off); off += (size_t)NBKT * BCAP * 4;
    int*  col   = (int*)(ws + off);  off += (size_t)NEDGE * 4;
    off = (off + 255) & ~(size_t)255;
    ushort* Xb   = (ushort*)(ws + off); off += (size_t)NNODE * F * 2;
    off = (off + 255) & ~(size_t)255;
    ushort* H1   = (ushort*)(ws + off); off += (size_t)NNODE * F * 2;
    off = (off + 255) & ~(size_t)255;
    ushort* H2   = (ushort*)(ws + off); off += (size_t)NNODE * F * 2;
    off = (off + 255) & ~(size_t)255;
    ushort* Agg  = (ushort*)(ws + off); off += (size_t)NNODE * F * 2;
    off = (off + 255) & ~(size_t)255;
    ushort* G3   = (ushort*)(ws + off); off += (size_t)NNODE * CLS * 2;
    off = (off + 255) & ~(size_t)255;
    ushort* H3   = (ushort*)(ws + off); off += (size_t)NNODE * CLS * 2;
    off = (off + 255) & ~(size_t)255;
    ushort* Wb1s = (ushort*)(ws + off); off += 16384 * 2;
    ushort* Wb1n = (ushort*)(ws + off); off += 16384 * 2;
    ushort* Wb2s = (ushort*)(ws + off); off += 16384 * 2;
    ushort* Wb2n = (ushort*)(ws + off); off += 16384 * 2;
    ushort* Wb3s = (ushort*)(ws + off); off += 2048 * 2;
    ushort* Wb3n = (ushort*)(ws + off); off += 2048 * 2;

    hipMemsetAsync(gcount, 0, 512 * 4, stream);

    k_prep<<<CASTB + 272, 256, 0, stream>>>(x, Xb, W1s, W1n, W2s, W2n, W3s, W3n,
                                            Wb1s, Wb1n, Wb2s, Wb2n, Wb3s, Wb3n);

    k_bin<<<NTB, 256, 0, stream>>>(src, dst, bins, gcount);
    k_bscan<<<1, 256, 0, stream>>>(gcount, ebase);
    k_build<<<NBKT, 256, 0, stream>>>(bins, gcount, ebase, rp, col);

    k_agg<<<NNODE / 16, 256, 0, stream>>>(Xb, rp, col, Agg);
    k_gemm128<<<(NNODE + 127) / 128, 256, 0, stream>>>(Xb, Agg, Wb1s, Wb1n, b1, H1);

    k_agg<<<NNODE / 16, 256, 0, stream>>>(H1, rp, col, Agg);
    k_gemm128<<<(NNODE + 127) / 128, 256, 0, stream>>>(H1, Agg, Wb2s, Wb2n, b2, H2);

    k_gemm16d<<<(NNODE + 255) / 256, 256, 0, stream>>>(H2, Wb3n, Wb3s, b3, G3, H3);
    k_agg16<<<(NNODE + 127) / 128, 256, 0, stream>>>(G3, rp, col, H3);

    k_score<<<(EPOS + ENEG + 255) / 256, 256, 0, stream>>>(H3, pos_u, pos_v,
                                                           neg_u, neg_v, out);
}

// Round 11
// 264.104 us; speedup vs baseline: 1.4580x; 1.0499x over previous
//
#include <hip/hip_runtime.h>

static constexpr int NNODE = 100000;
static constexpr int NEDGE = 1600000;
static constexpr int EPOS  = 100000;
static constexpr int ENEG  = 500000;
static constexpr int F     = 128;
static constexpr int CLS   = 16;
static constexpr int NBKT  = 392;      // buckets of 256 nodes (dst >> 8); 392*256 = 100352
static constexpr int BCAP  = 4608;     // bucket capacity (mean 4096, +8 sigma)
static constexpr int TILE  = 2048;     // edges per k_bin block
static constexpr int NTB   = (NEDGE + TILE - 1) / TILE;   // 782
static constexpr int CASTB = NNODE * F / 4 / 256;         // 12500 cast blocks

using bf16x8 = __attribute__((ext_vector_type(8))) short;
using f32x4  = __attribute__((ext_vector_type(4))) float;

// ---------------- bf16 helpers ----------------

__device__ __forceinline__ ushort f2b(float f) {           // f32 -> bf16 RNE
    unsigned u = __float_as_uint(f);
    unsigned r = u + 0x7fffu + ((u >> 16) & 1u);
    return (ushort)(r >> 16);
}
__device__ __forceinline__ float b2f(ushort h) {
    return __uint_as_float(((unsigned)h) << 16);
}

// cast X (blocks 0..CASTB) + repack weights (blocks CASTB..CASTB+272)
__global__ void k_prep(const float* __restrict__ x, ushort* __restrict__ xb,
                       const float* __restrict__ W1s, const float* __restrict__ W1n,
                       const float* __restrict__ W2s, const float* __restrict__ W2n,
                       const float* __restrict__ W3s, const float* __restrict__ W3n,
                       ushort* __restrict__ o1s, ushort* __restrict__ o1n,
                       ushort* __restrict__ o2s, ushort* __restrict__ o2n,
                       ushort* __restrict__ o3s, ushort* __restrict__ o3n) {
    const int t = threadIdx.x;
    if (blockIdx.x < CASTB) {
        const int i = blockIdx.x * 256 + t;
        float4 v = ((const float4*)x)[i];
        ushort4 o; o.x = f2b(v.x); o.y = f2b(v.y); o.z = f2b(v.z); o.w = f2b(v.w);
        ((ushort4*)xb)[i] = o;
        return;
    }
    const int b = blockIdx.x - CASTB;
    const float* src; ushort* dst; int C; int idx;
    if      (b < 64)  { src = W1s; dst = o1s; C = 128; idx = b * 256 + t; }
    else if (b < 128) { src = W1n; dst = o1n; C = 128; idx = (b - 64) * 256 + t; }
    else if (b < 192) { src = W2s; dst = o2s; C = 128; idx = (b - 128) * 256 + t; }
    else if (b < 256) { src = W2n; dst = o2n; C = 128; idx = (b - 192) * 256 + t; }
    else if (b < 264) { src = W3s; dst = o3s; C = 16;  idx = (b - 256) * 256 + t; }
    else              { src = W3n; dst = o3n; C = 16;  idx = (b - 264) * 256 + t; }
    const int k = idx / C, c = idx % C;
    dst[(k >> 3) * C * 8 + c * 8 + (k & 7)] = f2b(src[idx]);
}

// ---------------- CSR build: bucket binning (phase 1) ----------------

__global__ __launch_bounds__(256) void k_bin(
    const int* __restrict__ src, const int* __restrict__ dst,
    uint* __restrict__ bins, int* __restrict__ gcount) {
    __shared__ int  hist[NBKT];
    __shared__ int  lofs[NBKT];
    __shared__ int  gbase[NBKT];
    __shared__ int  run[NBKT];
    __shared__ int  tmp[256];
    __shared__ uint stage[TILE];
    const int tid = threadIdx.x;
    const int e0  = blockIdx.x * TILE;

    for (int i = tid; i < NBKT; i += 256) hist[i] = 0;
    __syncthreads();
    #pragma unroll
    for (int j = 0; j < TILE / 256; ++j) {
        const int e = e0 + j * 256 + tid;
        if (e < NEDGE) atomicAdd(&hist[dst[e] >> 8], 1);
    }
    __syncthreads();
    const int i0 = 2 * tid, i1 = 2 * tid + 1;
    const int a0 = (i0 < NBKT) ? hist[i0] : 0;
    const int a1 = (i1 < NBKT) ? hist[i1] : 0;
    tmp[tid] = a0 + a1;
    __syncthreads();
    for (int off = 1; off < 256; off <<= 1) {
        int y = (tid >= off) ? tmp[tid - off] : 0;
        __syncthreads();
        tmp[tid] += y;
        __syncthreads();
    }
    const int pbase = tid ? tmp[tid - 1] : 0;
    if (i0 < NBKT) { lofs[i0] = pbase;      run[i0] = pbase; }
    if (i1 < NBKT) { lofs[i1] = pbase + a0; run[i1] = pbase + a0; }
    __syncthreads();
    for (int i = tid; i < NBKT; i += 256)
        gbase[i] = (hist[i] > 0) ? atomicAdd(&gcount[i], hist[i]) : 0;
    __syncthreads();
    #pragma unroll
    for (int j = 0; j < TILE / 256; ++j) {
        const int e = e0 + j * 256 + tid;
        if (e < NEDGE) {
            const int d = dst[e];
            const int b = d >> 8;
            const int r = atomicAdd(&run[b], 1);
            stage[r] = (uint)(src[e] | ((d & 255) << 17));
        }
    }
    __syncthreads();
    const int total = lofs[NBKT - 1] + hist[NBKT - 1];
    for (int i = tid; i < total; i += 256) {
        int lo = 0, hi = NBKT - 1;                  // largest b with lofs[b] <= i
        while (lo < hi) {
            const int mid = (lo + hi + 1) >> 1;
            if (lofs[mid] <= i) lo = mid; else hi = mid - 1;
        }
        bins[(size_t)lo * BCAP + gbase[lo] + (i - lofs[lo])] = stage[i];
    }
}

// exclusive scan of gcount[NBKT] -> ebase[NBKT]
__global__ void k_bscan(const int* __restrict__ gcount, int* __restrict__ ebase) {
    __shared__ int s[256];
    const int t = threadIdx.x;
    const int i0 = 2 * t, i1 = 2 * t + 1;
    const int a0 = (i0 < NBKT) ? gcount[i0] : 0;
    const int a1 = (i1 < NBKT) ? gcount[i1] : 0;
    s[t] = a0 + a1;
    __syncthreads();
    for (int off = 1; off < 256; off <<= 1) {
        int y = (t >= off) ? s[t - off] : 0;
        __syncthreads();
        s[t] += y;
        __syncthreads();
    }
    const int pbase = t ? s[t - 1] : 0;
    if (i0 < NBKT) ebase[i0] = pbase;
    if (i1 < NBKT) ebase[i1] = pbase + a0;
}

// ---------------- CSR build: per-bucket degree/scan/scatter (phase 2) ----------------

__global__ __launch_bounds__(256) void k_build(
    const uint* __restrict__ bins, const int* __restrict__ gcount,
    const int* __restrict__ ebase, int* __restrict__ rp, int* __restrict__ col) {
    __shared__ int ldeg[256];
    __shared__ int lrp[256];
    const int tid = threadIdx.x;
    const int b   = blockIdx.x;
    const int nbase = b * 256;
    const int cnt   = gcount[b];
    const int eb    = ebase[b];
    const uint* mybins = bins + (size_t)b * BCAP;

    ldeg[tid] = 0;
    __syncthreads();
    for (int i = tid; i < cnt; i += 256)
        atomicAdd(&ldeg[(mybins[i] >> 17) & 255], 1);
    __syncthreads();
    const int x = ldeg[tid];
    lrp[tid] = x;
    __syncthreads();
    for (int off = 1; off < 256; off <<= 1) {
        int y = (tid >= off) ? lrp[tid - off] : 0;
        __syncthreads();
        lrp[tid] += y;
        __syncthreads();
    }
    const int excl = lrp[tid] - x;
    rp[nbase + tid] = eb + excl;
    ldeg[tid] = excl;                 // running counters
    __syncthreads();
    for (int i = tid; i < cnt; i += 256) {
        const uint v = mybins[i];
        const int dlow = (v >> 17) & 255;
        const int p = atomicAdd(&ldeg[dlow], 1);
        col[eb + p] = (int)(v & 0x1FFFF);
    }
    if (b == NBKT - 1 && tid == 0) rp[NBKT * 256] = eb + cnt;   // sentinel
}

// ---------------- fused gather-mean + dual MFMA GEMM, 16 rows/block ----------------
// Phase A: identical memory pattern to the proven k_agg (16 rows, 16 lanes/row,
// 4-way unroll) but lands the mean in a 4 KB swizzled LDS tile.
// Phase B: out = relu(self@Ws + agg@Wn + b); each of 4 waves does 16 rows x 32 cols.
// 6250 blocks, no bounds checks (100000 = 6250*16).

__global__ __launch_bounds__(256) void k_aggemm(
    const ushort* __restrict__ hin, const int* __restrict__ rp,
    const int* __restrict__ col, const ushort* __restrict__ Ws2,
    const ushort* __restrict__ Wn2, const float* __restrict__ bias,
    ushort* __restrict__ outb) {
    __shared__ ushort AggT[16 * 128];   // 4 KB, 16B slots XOR-swizzled by (row&7)
    const int tid = threadIdx.x;
    const int bbase = blockIdx.x * 16;

    // ---- phase A: gather-mean ----
    {
        const int lrow = tid >> 4;
        const int l16  = tid & 15;
        const int row  = bbase + lrow;
        const int p0 = rp[row];
        const int pe = rp[row + 1];
        const int d  = pe - p0;
        float s0[8] = {0, 0, 0, 0, 0, 0, 0, 0};
        float s1[8] = {0, 0, 0, 0, 0, 0, 0, 0};
        float s2[8] = {0, 0, 0, 0, 0, 0, 0, 0};
        float s3[8] = {0, 0, 0, 0, 0, 0, 0, 0};
        int p = p0;
        for (; p + 4 <= pe; p += 4) {
            const int u0 = col[p];
            const int u1 = col[p + 1];
            const int u2 = col[p + 2];
            const int u3 = col[p + 3];
            const bf16x8 a = *(const bf16x8*)(hin + (size_t)u0 * F + l16 * 8);
            const bf16x8 b = *(const bf16x8*)(hin + (size_t)u1 * F + l16 * 8);
            const bf16x8 c = *(const bf16x8*)(hin + (size_t)u2 * F + l16 * 8);
            const bf16x8 e = *(const bf16x8*)(hin + (size_t)u3 * F + l16 * 8);
            #pragma unroll
            for (int j = 0; j < 8; ++j) s0[j] += b2f((ushort)a[j]);
            #pragma unroll
            for (int j = 0; j < 8; ++j) s1[j] += b2f((ushort)b[j]);
            #pragma unroll
            for (int j = 0; j < 8; ++j) s2[j] += b2f((ushort)c[j]);
            #pragma unroll
            for (int j = 0; j < 8; ++j) s3[j] += b2f((ushort)e[j]);
        }
        for (; p < pe; ++p) {
            const bf16x8 a = *(const bf16x8*)(hin + (size_t)col[p] * F + l16 * 8);
            #pragma unroll
            for (int j = 0; j < 8; ++j) s0[j] += b2f((ushort)a[j]);
        }
        const float inv = d > 0 ? 1.0f / (float)d : 0.0f;
        bf16x8 o;
        #pragma unroll
        for (int j = 0; j < 8; ++j)
            o[j] = (short)f2b(((s0[j] + s1[j]) + (s2[j] + s3[j])) * inv);
        const int sbyte = lrow * 256 + ((l16 * 16) ^ ((lrow & 7) << 4));
        *(bf16x8*)((char*)AggT + sbyte) = o;
    }
    __syncthreads();

    // ---- phase B: dual GEMM (16 rows x 32 cols per wave) ----
    const int wv   = tid >> 6;
    const int lane = tid & 63;
    const int l16  = lane & 15;
    const int lk   = lane >> 4;

    f32x4 acc0 = (f32x4){0, 0, 0, 0};
    f32x4 acc1 = (f32x4){0, 0, 0, 0};
    const size_t ra = (size_t)(bbase + l16) * F + lk * 8;
    const int n0 = wv * 2, n1 = wv * 2 + 1;

    #pragma unroll
    for (int kb = 0; kb < 4; ++kb) {
        const bf16x8 as = *(const bf16x8*)(hin + ra + kb * 32);
        const int abyte = l16 * 256 + ((kb * 64 + lk * 16) ^ ((l16 & 7) << 4));
        const bf16x8 aa = *(const bf16x8*)((char*)AggT + abyte);
        const int kg = kb * 4 + lk;
        {
            const bf16x8 bs = *(const bf16x8*)&Ws2[kg * 1024 + (n0 * 16 + l16) * 8];
            const bf16x8 bn = *(const bf16x8*)&Wn2[kg * 1024 + (n0 * 16 + l16) * 8];
            acc0 = __builtin_amdgcn_mfma_f32_16x16x32_bf16(as, bs, acc0, 0, 0, 0);
            acc0 = __builtin_amdgcn_mfma_f32_16x16x32_bf16(aa, bn, acc0, 0, 0, 0);
        }
        {
            const bf16x8 bs = *(const bf16x8*)&Ws2[kg * 1024 + (n1 * 16 + l16) * 8];
            const bf16x8 bn = *(const bf16x8*)&Wn2[kg * 1024 + (n1 * 16 + l16) * 8];
            acc1 = __builtin_amdgcn_mfma_f32_16x16x32_bf16(as, bs, acc1, 0, 0, 0);
            acc1 = __builtin_amdgcn_mfma_f32_16x16x32_bf16(aa, bn, acc1, 0, 0, 0);
        }
    }

    {
        const int c0 = n0 * 16 + l16;
        const int c1 = n1 * 16 + l16;
        const float bv0 = bias[c0];
        const float bv1 = bias[c1];
        #pragma unroll
        for (int j = 0; j < 4; ++j) {
            const size_t rr = (size_t)(bbase + lk * 4 + j) * F;
            outb[rr + c0] = f2b(fmaxf(acc0[j] + bv0, 0.f));
            outb[rr + c1] = f2b(fmaxf(acc1[j] + bv1, 0.f));
        }
    }
}

// width-16 aggregation for G3, RMW-adds mean into H3 (bf16). 2 lanes/row.
__global__ __launch_bounds__(256) void k_agg16(
    const ushort* __restrict__ G, const int* __restrict__ rp,
    const int* __restrict__ col, ushort* __restrict__ H3) {
    const int tid  = threadIdx.x;
    const int row  = blockIdx.x * 128 + (tid >> 1);
    const int half = tid & 1;
    if (row >= NNODE) return;
    const int p0 = rp[row];
    const int pe = rp[row + 1];
    const int d  = pe - p0;
    if (d == 0) return;
    float s0[8] = {0, 0, 0, 0, 0, 0, 0, 0};
    float s1[8] = {0, 0, 0, 0, 0, 0, 0, 0};
    float s2[8] = {0, 0, 0, 0, 0, 0, 0, 0};
    float s3[8] = {0, 0, 0, 0, 0, 0, 0, 0};
    int p = p0;
    for (; p + 4 <= pe; p += 4) {
        const int u0 = col[p];
        const int u1 = col[p + 1];
        const int u2 = col[p + 2];
        const int u3 = col[p + 3];
        const bf16x8 a = *(const bf16x8*)(G + (size_t)u0 * CLS + half * 8);
        const bf16x8 b = *(const bf16x8*)(G + (size_t)u1 * CLS + half * 8);
        const bf16x8 c = *(const bf16x8*)(G + (size_t)u2 * CLS + half * 8);
        const bf16x8 e = *(const bf16x8*)(G + (size_t)u3 * CLS + half * 8);
        #pragma unroll
        for (int j = 0; j < 8; ++j) s0[j] += b2f((ushort)a[j]);
        #pragma unroll
        for (int j = 0; j < 8; ++j) s1[j] += b2f((ushort)b[j]);
        #pragma unroll
        for (int j = 0; j < 8; ++j) s2[j] += b2f((ushort)c[j]);
        #pragma unroll
        for (int j = 0; j < 8; ++j) s3[j] += b2f((ushort)e[j]);
    }
    for (; p < pe; ++p) {
        const bf16x8 a = *(const bf16x8*)(G + (size_t)col[p] * CLS + half * 8);
        #pragma unroll
        for (int j = 0; j < 8; ++j) s0[j] += b2f((ushort)a[j]);
    }
    const float inv = 1.0f / (float)d;
    ushort* dst = H3 + (size_t)row * CLS + half * 8;
    const bf16x8 cur = *(const bf16x8*)dst;
    bf16x8 o;
    #pragma unroll
    for (int j = 0; j < 8; ++j)
        o[j] = (short)f2b(b2f((ushort)cur[j]) +
                          ((s0[j] + s1[j]) + (s2[j] + s3[j])) * inv);
    *(bf16x8*)dst = o;
}

// ---------------- dual MFMA GEMM: G3 = A@Wn3, H3 = A@Ws3 + b (both bf16), N=16 ----------------

__global__ __launch_bounds__(256) void k_gemm16d(
    const ushort* __restrict__ A, const ushort* __restrict__ Wn2,
    const ushort* __restrict__ Ws2, const float* __restrict__ bias,
    ushort* __restrict__ G3, ushort* __restrict__ H3) {
    __shared__ ushort Wn_l[2048];
    __shared__ ushort Ws_l[2048];
    const int tid  = threadIdx.x;
    const int wv   = tid >> 6;
    const int lane = tid & 63;
    const int l16  = lane & 15;
    const int lk   = lane >> 4;
    const int rbase = blockIdx.x * 256 + wv * 64;

    *(bf16x8*)&Wn_l[tid * 8] = *(const bf16x8*)&Wn2[tid * 8];
    *(bf16x8*)&Ws_l[tid * 8] = *(const bf16x8*)&Ws2[tid * 8];
    __syncthreads();

    f32x4 accN[4], accS[4];
    #pragma unroll
    for (int rt = 0; rt < 4; ++rt) { accN[rt] = (f32x4){0,0,0,0}; accS[rt] = (f32x4){0,0,0,0}; }

    #pragma unroll
    for (int kb = 0; kb < 4; ++kb) {
        const int kg = kb * 4 + lk;
        const bf16x8 bn = *(const bf16x8*)&Wn_l[kg * 128 + l16 * 8];
        const bf16x8 bs = *(const bf16x8*)&Ws_l[kg * 128 + l16 * 8];
        #pragma unroll
        for (int rt = 0; rt < 4; ++rt) {
            int row = rbase + rt * 16 + l16;
            if (row >= NNODE) row = NNODE - 1;
            const bf16x8 a = *(const bf16x8*)(A + (size_t)row * F + kb * 32 + lk * 8);
            accN[rt] = __builtin_amdgcn_mfma_f32_16x16x32_bf16(a, bn, accN[rt], 0, 0, 0);
            accS[rt] = __builtin_amdgcn_mfma_f32_16x16x32_bf16(a, bs, accS[rt], 0, 0, 0);
        }
    }

    const float bv = bias[l16];
    #pragma unroll
    for (int rt = 0; rt < 4; ++rt) {
        #pragma unroll
        for (int j = 0; j < 4; ++j) {
            const int rr = rbase + rt * 16 + lk * 4 + j;
            if (rr < NNODE) {
                G3[(size_t)rr * CLS + l16] = f2b(accN[rt][j]);
                H3[(size_t)rr * CLS + l16] = f2b(accS[rt][j] + bv);
            }
        }
    }
}

// ---------------- edge scoring (bf16 H3) ----------------

__global__ void k_score(const ushort* __restrict__ H3,
                        const int* __restrict__ pu, const int* __restrict__ pv,
                        const int* __restrict__ nu, const int* __restrict__ nv,
                        float* __restrict__ out) {
    int i = blockIdx.x * 256 + threadIdx.x;
    if (i >= EPOS + ENEG) return;
    int u, v, o;
    if (i < EPOS) { u = pu[i]; v = pv[i]; o = i; }
    else { int j = i - EPOS; u = nu[j]; v = nv[j]; o = EPOS + j; }
    const bf16x8 a0 = *(const bf16x8*)(H3 + (size_t)u * CLS);
    const bf16x8 a1 = *(const bf16x8*)(H3 + (size_t)u * CLS + 8);
    const bf16x8 b0 = *(const bf16x8*)(H3 + (size_t)v * CLS);
    const bf16x8 b1 = *(const bf16x8*)(H3 + (size_t)v * CLS + 8);
    float s = 0.f;
    #pragma unroll
    for (int r = 0; r < 8; ++r) s += b2f((ushort)a0[r]) * b2f((ushort)b0[r]);
    #pragma unroll
    for (int r = 0; r < 8; ++r) s += b2f((ushort)a1[r]) * b2f((ushort)b1[r]);
    out[o] = s;
}

// ---------------- launch ----------------

extern "C" void kernel_launch(void* const* d_in, const int* in_sizes, int n_in,
                              void* d_out, int out_size, void* d_ws, size_t ws_size,
                              hipStream_t stream) {
    const float* x     = (const float*)d_in[0];
    const int*   src   = (const int*)d_in[1];
    const int*   dst   = (const int*)d_in[2];
    const int*   pos_u = (const int*)d_in[3];
    const int*   pos_v = (const int*)d_in[4];
    const int*   neg_u = (const int*)d_in[5];
    const int*   neg_v = (const int*)d_in[6];
    const float* W1s = (const float*)d_in[7];
    const float* W1n = (const float*)d_in[8];
    const float* b1  = (const float*)d_in[9];
    const float* W2s = (const float*)d_in[10];
    const float* W2n = (const float*)d_in[11];
    const float* b2  = (const float*)d_in[12];
    const float* W3s = (const float*)d_in[13];
    const float* W3n = (const float*)d_in[14];
    const float* b3  = (const float*)d_in[15];
    float* out = (float*)d_out;

    char* ws = (char*)d_ws;
    size_t off = 0;
    int* rp     = (int*)(ws + off); off += (size_t)(NBKT * 256 + 256) * 4;
    int* gcount = (int*)(ws + off); off += 512 * 4;
    int* ebase  = (int*)(ws + off); off += 512 * 4;
    off = (off + 255) & ~(size_t)255;
    uint* bins  = (uint*)(ws + off); off += (size_t)NBKT * BCAP * 4;
    int*  col   = (int*)(ws + off);  off += (size_t)NEDGE * 4;
    off = (off + 255) & ~(size_t)255;
    ushort* Xb   = (ushort*)(ws + off); off += (size_t)NNODE * F * 2;
    off = (off + 255) & ~(size_t)255;
    ushort* H1   = (ushort*)(ws + off); off += (size_t)NNODE * F * 2;
    off = (off + 255) & ~(size_t)255;
    ushort* H2   = (ushort*)(ws + off); off += (size_t)NNODE * F * 2;
    off = (off + 255) & ~(size_t)255;
    ushort* G3   = (ushort*)(ws + off); off += (size_t)NNODE * CLS * 2;
    off = (off + 255) & ~(size_t)255;
    ushort* H3   = (ushort*)(ws + off); off += (size_t)NNODE * CLS * 2;
    off = (off + 255) & ~(size_t)255;
    ushort* Wb1s = (ushort*)(ws + off); off += 16384 * 2;
    ushort* Wb1n = (ushort*)(ws + off); off += 16384 * 2;
    ushort* Wb2s = (ushort*)(ws + off); off += 16384 * 2;
    ushort* Wb2n = (ushort*)(ws + off); off += 16384 * 2;
    ushort* Wb3s = (ushort*)(ws + off); off += 2048 * 2;
    ushort* Wb3n = (ushort*)(ws + off); off += 2048 * 2;

    hipMemsetAsync(gcount, 0, 512 * 4, stream);

    k_prep<<<CASTB + 272, 256, 0, stream>>>(x, Xb, W1s, W1n, W2s, W2n, W3s, W3n,
                                            Wb1s, Wb1n, Wb2s, Wb2n, Wb3s, Wb3n);

    k_bin<<<NTB, 256, 0, stream>>>(src, dst, bins, gcount);
    k_bscan<<<1, 256, 0, stream>>>(gcount, ebase);
    k_build<<<NBKT, 256, 0, stream>>>(bins, gcount, ebase, rp, col);

    k_aggemm<<<NNODE / 16, 256, 0, stream>>>(Xb, rp, col, Wb1s, Wb1n, b1, H1);
    k_aggemm<<<NNODE / 16, 256, 0, stream>>>(H1, rp, col, Wb2s, Wb2n, b2, H2);

    k_gemm16d<<<(NNODE + 255) / 256, 256, 0, stream>>>(H2, Wb3n, Wb3s, b3, G3, H3);
    k_agg16<<<(NNODE + 127) / 128, 256, 0, stream>>>(G3, rp, col, H3);

    k_score<<<(EPOS + ENEG + 255) / 256, 256, 0, stream>>>(H3, pos_u, pos_v,
                                                           neg_u, neg_v, out);
}

// Round 12
// 254.737 us; speedup vs baseline: 1.5116x; 1.0368x over previous
//
#include <hip/hip_runtime.h>

static constexpr int NNODE = 100000;
static constexpr int NEDGE = 1600000;
static constexpr int EPOS  = 100000;
static constexpr int ENEG  = 500000;
static constexpr int F     = 128;
static constexpr int CLS   = 16;
static constexpr int NBKT  = 392;      // buckets of 256 nodes (dst >> 8); 392*256 = 100352
static constexpr int BCAP  = 4608;     // bucket capacity (mean 4096, +8 sigma)
static constexpr int TILE  = 2048;     // edges per bin block
static constexpr int NTB   = (NEDGE + TILE - 1) / TILE;   // 782
static constexpr int CASTB = NNODE * F / 4 / 256;         // 12500 cast blocks

using bf16x8 = __attribute__((ext_vector_type(8))) short;
using f32x4  = __attribute__((ext_vector_type(4))) float;

// ---------------- bf16 helpers ----------------

__device__ __forceinline__ ushort f2b(float f) {           // f32 -> bf16 RNE
    unsigned u = __float_as_uint(f);
    unsigned r = u + 0x7fffu + ((u >> 16) & 1u);
    return (ushort)(r >> 16);
}
__device__ __forceinline__ float b2f(ushort h) {
    return __uint_as_float(((unsigned)h) << 16);
}

// ---------------- merged front-end: edge binning + x cast + weight repack ----------------
// blocks [0, NTB): bin;  [NTB, NTB+CASTB): cast;  rest: weight repack.

__global__ __launch_bounds__(256) void k_front(
    const int* __restrict__ esrc, const int* __restrict__ edst,
    uint* __restrict__ bins, int* __restrict__ gcount,
    const float* __restrict__ x, ushort* __restrict__ xb,
    const float* __restrict__ W1s, const float* __restrict__ W1n,
    const float* __restrict__ W2s, const float* __restrict__ W2n,
    const float* __restrict__ W3s, const float* __restrict__ W3n,
    ushort* __restrict__ o1s, ushort* __restrict__ o1n,
    ushort* __restrict__ o2s, ushort* __restrict__ o2n,
    ushort* __restrict__ o3s, ushort* __restrict__ o3n) {
    const int tid = threadIdx.x;

    if (blockIdx.x >= NTB) {
        const int pb = blockIdx.x - NTB;
        if (pb < CASTB) {
            const int i = pb * 256 + tid;
            float4 v = ((const float4*)x)[i];
            ushort4 o; o.x = f2b(v.x); o.y = f2b(v.y); o.z = f2b(v.z); o.w = f2b(v.w);
            ((ushort4*)xb)[i] = o;
            return;
        }
        const int b = pb - CASTB;
        const float* src; ushort* dst; int C; int idx;
        if      (b < 64)  { src = W1s; dst = o1s; C = 128; idx = b * 256 + tid; }
        else if (b < 128) { src = W1n; dst = o1n; C = 128; idx = (b - 64) * 256 + tid; }
        else if (b < 192) { src = W2s; dst = o2s; C = 128; idx = (b - 128) * 256 + tid; }
        else if (b < 256) { src = W2n; dst = o2n; C = 128; idx = (b - 192) * 256 + tid; }
        else if (b < 264) { src = W3s; dst = o3s; C = 16;  idx = (b - 256) * 256 + tid; }
        else              { src = W3n; dst = o3n; C = 16;  idx = (b - 264) * 256 + tid; }
        const int k = idx / C, c = idx % C;
        dst[(k >> 3) * C * 8 + c * 8 + (k & 7)] = f2b(src[idx]);
        return;
    }

    // ---- bin work ----
    __shared__ int  hist[NBKT];
    __shared__ int  lofs[NBKT];
    __shared__ int  gbase[NBKT];
    __shared__ int  run[NBKT];
    __shared__ int  tmp[256];
    __shared__ uint stage[TILE];
    const int e0 = blockIdx.x * TILE;

    for (int i = tid; i < NBKT; i += 256) hist[i] = 0;
    __syncthreads();
    #pragma unroll
    for (int j = 0; j < TILE / 256; ++j) {
        const int e = e0 + j * 256 + tid;
        if (e < NEDGE) atomicAdd(&hist[edst[e] >> 8], 1);
    }
    __syncthreads();
    const int i0 = 2 * tid, i1 = 2 * tid + 1;
    const int a0 = (i0 < NBKT) ? hist[i0] : 0;
    const int a1 = (i1 < NBKT) ? hist[i1] : 0;
    tmp[tid] = a0 + a1;
    __syncthreads();
    for (int off = 1; off < 256; off <<= 1) {
        int y = (tid >= off) ? tmp[tid - off] : 0;
        __syncthreads();
        tmp[tid] += y;
        __syncthreads();
    }
    const int pbase = tid ? tmp[tid - 1] : 0;
    if (i0 < NBKT) { lofs[i0] = pbase;      run[i0] = pbase; }
    if (i1 < NBKT) { lofs[i1] = pbase + a0; run[i1] = pbase + a0; }
    __syncthreads();
    for (int i = tid; i < NBKT; i += 256)
        gbase[i] = (hist[i] > 0) ? atomicAdd(&gcount[i], hist[i]) : 0;
    __syncthreads();
    #pragma unroll
    for (int j = 0; j < TILE / 256; ++j) {
        const int e = e0 + j * 256 + tid;
        if (e < NEDGE) {
            const int d = edst[e];
            const int b = d >> 8;
            const int r = atomicAdd(&run[b], 1);
            stage[r] = (uint)(esrc[e] | ((d & 255) << 17));
        }
    }
    __syncthreads();
    const int total = lofs[NBKT - 1] + hist[NBKT - 1];
    for (int i = tid; i < total; i += 256) {
        int lo = 0, hi = NBKT - 1;                  // largest b with lofs[b] <= i
        while (lo < hi) {
            const int mid = (lo + hi + 1) >> 1;
            if (lofs[mid] <= i) lo = mid; else hi = mid - 1;
        }
        bins[(size_t)lo * BCAP + gbase[lo] + (i - lofs[lo])] = stage[i];
    }
}

// exclusive scan of gcount[NBKT] -> ebase[NBKT]
__global__ void k_bscan(const int* __restrict__ gcount, int* __restrict__ ebase) {
    __shared__ int s[256];
    const int t = threadIdx.x;
    const int i0 = 2 * t, i1 = 2 * t + 1;
    const int a0 = (i0 < NBKT) ? gcount[i0] : 0;
    const int a1 = (i1 < NBKT) ? gcount[i1] : 0;
    s[t] = a0 + a1;
    __syncthreads();
    for (int off = 1; off < 256; off <<= 1) {
        int y = (t >= off) ? s[t - off] : 0;
        __syncthreads();
        s[t] += y;
        __syncthreads();
    }
    const int pbase = t ? s[t - 1] : 0;
    if (i0 < NBKT) ebase[i0] = pbase;
    if (i1 < NBKT) ebase[i1] = pbase + a0;
}

// ---------------- CSR build: per-bucket degree/scan/scatter (phase 2) ----------------

__global__ __launch_bounds__(256) void k_build(
    const uint* __restrict__ bins, const int* __restrict__ gcount,
    const int* __restrict__ ebase, int* __restrict__ rp, int* __restrict__ col) {
    __shared__ int ldeg[256];
    __shared__ int lrp[256];
    const int tid = threadIdx.x;
    const int b   = blockIdx.x;
    const int nbase = b * 256;
    const int cnt   = gcount[b];
    const int eb    = ebase[b];
    const uint* mybins = bins + (size_t)b * BCAP;

    ldeg[tid] = 0;
    __syncthreads();
    for (int i = tid; i < cnt; i += 256)
        atomicAdd(&ldeg[(mybins[i] >> 17) & 255], 1);
    __syncthreads();
    const int x = ldeg[tid];
    lrp[tid] = x;
    __syncthreads();
    for (int off = 1; off < 256; off <<= 1) {
        int y = (tid >= off) ? lrp[tid - off] : 0;
        __syncthreads();
        lrp[tid] += y;
        __syncthreads();
    }
    const int excl = lrp[tid] - x;
    rp[nbase + tid] = eb + excl;
    ldeg[tid] = excl;                 // running counters
    __syncthreads();
    for (int i = tid; i < cnt; i += 256) {
        const uint v = mybins[i];
        const int dlow = (v >> 17) & 255;
        const int p = atomicAdd(&ldeg[dlow], 1);
        col[eb + p] = (int)(v & 0x1FFFF);
    }
    if (b == NBKT - 1 && tid == 0) rp[NBKT * 256] = eb + cnt;   // sentinel
}

// ---------------- fused gather-mean + dual MFMA GEMM, 16 rows/block ----------------
// Phase A: gather-mean into 4 KB swizzled LDS (proven k_agg memory pattern).
// Self@Ws MFMAs issue BEFORE the barrier (no LDS dependency) so early waves
// compute instead of idling; only agg@Wn waits for the tile.

__global__ __launch_bounds__(256) void k_aggemm(
    const ushort* __restrict__ hin, const int* __restrict__ rp,
    const int* __restrict__ col, const ushort* __restrict__ Ws2,
    const ushort* __restrict__ Wn2, const float* __restrict__ bias,
    ushort* __restrict__ outb) {
    __shared__ ushort AggT[16 * 128];   // 4 KB, 16B slots XOR-swizzled by (row&7)
    const int tid = threadIdx.x;
    const int bbase = blockIdx.x * 16;

    // ---- phase A: gather-mean ----
    {
        const int lrow = tid >> 4;
        const int l16  = tid & 15;
        const int row  = bbase + lrow;
        const int p0 = rp[row];
        const int pe = rp[row + 1];
        const int d  = pe - p0;
        float s0[8] = {0, 0, 0, 0, 0, 0, 0, 0};
        float s1[8] = {0, 0, 0, 0, 0, 0, 0, 0};
        float s2[8] = {0, 0, 0, 0, 0, 0, 0, 0};
        float s3[8] = {0, 0, 0, 0, 0, 0, 0, 0};
        int p = p0;
        for (; p + 4 <= pe; p += 4) {
            const int u0 = col[p];
            const int u1 = col[p + 1];
            const int u2 = col[p + 2];
            const int u3 = col[p + 3];
            const bf16x8 a = *(const bf16x8*)(hin + (size_t)u0 * F + l16 * 8);
            const bf16x8 b = *(const bf16x8*)(hin + (size_t)u1 * F + l16 * 8);
            const bf16x8 c = *(const bf16x8*)(hin + (size_t)u2 * F + l16 * 8);
            const bf16x8 e = *(const bf16x8*)(hin + (size_t)u3 * F + l16 * 8);
            #pragma unroll
            for (int j = 0; j < 8; ++j) s0[j] += b2f((ushort)a[j]);
            #pragma unroll
            for (int j = 0; j < 8; ++j) s1[j] += b2f((ushort)b[j]);
            #pragma unroll
            for (int j = 0; j < 8; ++j) s2[j] += b2f((ushort)c[j]);
            #pragma unroll
            for (int j = 0; j < 8; ++j) s3[j] += b2f((ushort)e[j]);
        }
        for (; p < pe; ++p) {
            const bf16x8 a = *(const bf16x8*)(hin + (size_t)col[p] * F + l16 * 8);
            #pragma unroll
            for (int j = 0; j < 8; ++j) s0[j] += b2f((ushort)a[j]);
        }
        const float inv = d > 0 ? 1.0f / (float)d : 0.0f;
        bf16x8 o;
        #pragma unroll
        for (int j = 0; j < 8; ++j)
            o[j] = (short)f2b(((s0[j] + s1[j]) + (s2[j] + s3[j])) * inv);
        const int sbyte = lrow * 256 + ((l16 * 16) ^ ((lrow & 7) << 4));
        *(bf16x8*)((char*)AggT + sbyte) = o;
    }

    // ---- phase B1: self @ Ws (no LDS dependency -> before barrier) ----
    const int wv   = tid >> 6;
    const int lane = tid & 63;
    const int l16  = lane & 15;
    const int lk   = lane >> 4;
    const int n0 = wv * 2, n1 = wv * 2 + 1;
    const size_t ra = (size_t)(bbase + l16) * F + lk * 8;

    f32x4 acc0 = (f32x4){0, 0, 0, 0};
    f32x4 acc1 = (f32x4){0, 0, 0, 0};

    #pragma unroll
    for (int kb = 0; kb < 4; ++kb) {
        const bf16x8 as = *(const bf16x8*)(hin + ra + kb * 32);
        const int kg = kb * 4 + lk;
        const bf16x8 bs0 = *(const bf16x8*)&Ws2[kg * 1024 + (n0 * 16 + l16) * 8];
        const bf16x8 bs1 = *(const bf16x8*)&Ws2[kg * 1024 + (n1 * 16 + l16) * 8];
        acc0 = __builtin_amdgcn_mfma_f32_16x16x32_bf16(as, bs0, acc0, 0, 0, 0);
        acc1 = __builtin_amdgcn_mfma_f32_16x16x32_bf16(as, bs1, acc1, 0, 0, 0);
    }

    __syncthreads();

    // ---- phase B2: agg @ Wn (reads the LDS tile) ----
    #pragma unroll
    for (int kb = 0; kb < 4; ++kb) {
        const int abyte = l16 * 256 + ((kb * 64 + lk * 16) ^ ((l16 & 7) << 4));
        const bf16x8 aa = *(const bf16x8*)((char*)AggT + abyte);
        const int kg = kb * 4 + lk;
        const bf16x8 bn0 = *(const bf16x8*)&Wn2[kg * 1024 + (n0 * 16 + l16) * 8];
        const bf16x8 bn1 = *(const bf16x8*)&Wn2[kg * 1024 + (n1 * 16 + l16) * 8];
        acc0 = __builtin_amdgcn_mfma_f32_16x16x32_bf16(aa, bn0, acc0, 0, 0, 0);
        acc1 = __builtin_amdgcn_mfma_f32_16x16x32_bf16(aa, bn1, acc1, 0, 0, 0);
    }

    {
        const int c0 = n0 * 16 + l16;
        const int c1 = n1 * 16 + l16;
        const float bv0 = bias[c0];
        const float bv1 = bias[c1];
        #pragma unroll
        for (int j = 0; j < 4; ++j) {
            const size_t rr = (size_t)(bbase + lk * 4 + j) * F;
            outb[rr + c0] = f2b(fmaxf(acc0[j] + bv0, 0.f));
            outb[rr + c1] = f2b(fmaxf(acc1[j] + bv1, 0.f));
        }
    }
}

// width-16 aggregation for G3, RMW-adds mean into H3 (bf16). 2 lanes/row.
__global__ __launch_bounds__(256) void k_agg16(
    const ushort* __restrict__ G, const int* __restrict__ rp,
    const int* __restrict__ col, ushort* __restrict__ H3) {
    const int tid  = threadIdx.x;
    const int row  = blockIdx.x * 128 + (tid >> 1);
    const int half = tid & 1;
    if (row >= NNODE) return;
    const int p0 = rp[row];
    const int pe = rp[row + 1];
    const int d  = pe - p0;
    if (d == 0) return;
    float s0[8] = {0, 0, 0, 0, 0, 0, 0, 0};
    float s1[8] = {0, 0, 0, 0, 0, 0, 0, 0};
    float s2[8] = {0, 0, 0, 0, 0, 0, 0, 0};
    float s3[8] = {0, 0, 0, 0, 0, 0, 0, 0};
    int p = p0;
    for (; p + 4 <= pe; p += 4) {
        const int u0 = col[p];
        const int u1 = col[p + 1];
        const int u2 = col[p + 2];
        const int u3 = col[p + 3];
        const bf16x8 a = *(const bf16x8*)(G + (size_t)u0 * CLS + half * 8);
        const bf16x8 b = *(const bf16x8*)(G + (size_t)u1 * CLS + half * 8);
        const bf16x8 c = *(const bf16x8*)(G + (size_t)u2 * CLS + half * 8);
        const bf16x8 e = *(const bf16x8*)(G + (size_t)u3 * CLS + half * 8);
        #pragma unroll
        for (int j = 0; j < 8; ++j) s0[j] += b2f((ushort)a[j]);
        #pragma unroll
        for (int j = 0; j < 8; ++j) s1[j] += b2f((ushort)b[j]);
        #pragma unroll
        for (int j = 0; j < 8; ++j) s2[j] += b2f((ushort)c[j]);
        #pragma unroll
        for (int j = 0; j < 8; ++j) s3[j] += b2f((ushort)e[j]);
    }
    for (; p < pe; ++p) {
        const bf16x8 a = *(const bf16x8*)(G + (size_t)col[p] * CLS + half * 8);
        #pragma unroll
        for (int j = 0; j < 8; ++j) s0[j] += b2f((ushort)a[j]);
    }
    const float inv = 1.0f / (float)d;
    ushort* dst = H3 + (size_t)row * CLS + half * 8;
    const bf16x8 cur = *(const bf16x8*)dst;
    bf16x8 o;
    #pragma unroll
    for (int j = 0; j < 8; ++j)
        o[j] = (short)f2b(b2f((ushort)cur[j]) +
                          ((s0[j] + s1[j]) + (s2[j] + s3[j])) * inv);
    *(bf16x8*)dst = o;
}

// ---------------- dual MFMA GEMM: G3 = A@Wn3, H3 = A@Ws3 + b (both bf16), N=16 ----------------

__global__ __launch_bounds__(256) void k_gemm16d(
    const ushort* __restrict__ A, const ushort* __restrict__ Wn2,
    const ushort* __restrict__ Ws2, const float* __restrict__ bias,
    ushort* __restrict__ G3, ushort* __restrict__ H3) {
    __shared__ ushort Wn_l[2048];
    __shared__ ushort Ws_l[2048];
    const int tid  = threadIdx.x;
    const int wv   = tid >> 6;
    const int lane = tid & 63;
    const int l16  = lane & 15;
    const int lk   = lane >> 4;
    const int rbase = blockIdx.x * 256 + wv * 64;

    *(bf16x8*)&Wn_l[tid * 8] = *(const bf16x8*)&Wn2[tid * 8];
    *(bf16x8*)&Ws_l[tid * 8] = *(const bf16x8*)&Ws2[tid * 8];
    __syncthreads();

    f32x4 accN[4], accS[4];
    #pragma unroll
    for (int rt = 0; rt < 4; ++rt) { accN[rt] = (f32x4){0,0,0,0}; accS[rt] = (f32x4){0,0,0,0}; }

    #pragma unroll
    for (int kb = 0; kb < 4; ++kb) {
        const int kg = kb * 4 + lk;
        const bf16x8 bn = *(const bf16x8*)&Wn_l[kg * 128 + l16 * 8];
        const bf16x8 bs = *(const bf16x8*)&Ws_l[kg * 128 + l16 * 8];
        #pragma unroll
        for (int rt = 0; rt < 4; ++rt) {
            int row = rbase + rt * 16 + l16;
            if (row >= NNODE) row = NNODE - 1;
            const bf16x8 a = *(const bf16x8*)(A + (size_t)row * F + kb * 32 + lk * 8);
            accN[rt] = __builtin_amdgcn_mfma_f32_16x16x32_bf16(a, bn, accN[rt], 0, 0, 0);
            accS[rt] = __builtin_amdgcn_mfma_f32_16x16x32_bf16(a, bs, accS[rt], 0, 0, 0);
        }
    }

    const float bv = bias[l16];
    #pragma unroll
    for (int rt = 0; rt < 4; ++rt) {
        #pragma unroll
        for (int j = 0; j < 4; ++j) {
            const int rr = rbase + rt * 16 + lk * 4 + j;
            if (rr < NNODE) {
                G3[(size_t)rr * CLS + l16] = f2b(accN[rt][j]);
                H3[(size_t)rr * CLS + l16] = f2b(accS[rt][j] + bv);
            }
        }
    }
}

// ---------------- edge scoring (bf16 H3) ----------------

__global__ void k_score(const ushort* __restrict__ H3,
                        const int* __restrict__ pu, const int* __restrict__ pv,
                        const int* __restrict__ nu, const int* __restrict__ nv,
                        float* __restrict__ out) {
    int i = blockIdx.x * 256 + threadIdx.x;
    if (i >= EPOS + ENEG) return;
    int u, v, o;
    if (i < EPOS) { u = pu[i]; v = pv[i]; o = i; }
    else { int j = i - EPOS; u = nu[j]; v = nv[j]; o = EPOS + j; }
    const bf16x8 a0 = *(const bf16x8*)(H3 + (size_t)u * CLS);
    const bf16x8 a1 = *(const bf16x8*)(H3 + (size_t)u * CLS + 8);
    const bf16x8 b0 = *(const bf16x8*)(H3 + (size_t)v * CLS);
    const bf16x8 b1 = *(const bf16x8*)(H3 + (size_t)v * CLS + 8);
    float s = 0.f;
    #pragma unroll
    for (int r = 0; r < 8; ++r) s += b2f((ushort)a0[r]) * b2f((ushort)b0[r]);
    #pragma unroll
    for (int r = 0; r < 8; ++r) s += b2f((ushort)a1[r]) * b2f((ushort)b1[r]);
    out[o] = s;
}

// ---------------- launch ----------------

extern "C" void kernel_launch(void* const* d_in, const int* in_sizes, int n_in,
                              void* d_out, int out_size, void* d_ws, size_t ws_size,
                              hipStream_t stream) {
    const float* x     = (const float*)d_in[0];
    const int*   src   = (const int*)d_in[1];
    const int*   dst   = (const int*)d_in[2];
    const int*   pos_u = (const int*)d_in[3];
    const int*   pos_v = (const int*)d_in[4];
    const int*   neg_u = (const int*)d_in[5];
    const int*   neg_v = (const int*)d_in[6];
    const float* W1s = (const float*)d_in[7];
    const float* W1n = (const float*)d_in[8];
    const float* b1  = (const float*)d_in[9];
    const float* W2s = (const float*)d_in[10];
    const float* W2n = (const float*)d_in[11];
    const float* b2  = (const float*)d_in[12];
    const float* W3s = (const float*)d_in[13];
    const float* W3n = (const float*)d_in[14];
    const float* b3  = (const float*)d_in[15];
    float* out = (float*)d_out;

    char* ws = (char*)d_ws;
    size_t off = 0;
    int* rp     = (int*)(ws + off); off += (size_t)(NBKT * 256 + 256) * 4;
    int* gcount = (int*)(ws + off); off += 512 * 4;
    int* ebase  = (int*)(ws + off); off += 512 * 4;
    off = (off + 255) & ~(size_t)255;
    uint* bins  = (uint*)(ws + off); off += (size_t)NBKT * BCAP * 4;
    int*  col   = (int*)(ws + off);  off += (size_t)NEDGE * 4;
    off = (off + 255) & ~(size_t)255;
    ushort* Xb   = (ushort*)(ws + off); off += (size_t)NNODE * F * 2;
    off = (off + 255) & ~(size_t)255;
    ushort* H1   = (ushort*)(ws + off); off += (size_t)NNODE * F * 2;
    off = (off + 255) & ~(size_t)255;
    ushort* H2   = (ushort*)(ws + off); off += (size_t)NNODE * F * 2;
    off = (off + 255) & ~(size_t)255;
    ushort* G3   = (ushort*)(ws + off); off += (size_t)NNODE * CLS * 2;
    off = (off + 255) & ~(size_t)255;
    ushort* H3   = (ushort*)(ws + off); off += (size_t)NNODE * CLS * 2;
    off = (off + 255) & ~(size_t)255;
    ushort* Wb1s = (ushort*)(ws + off); off += 16384 * 2;
    ushort* Wb1n = (ushort*)(ws + off); off += 16384 * 2;
    ushort* Wb2s = (ushort*)(ws + off); off += 16384 * 2;
    ushort* Wb2n = (ushort*)(ws + off); off += 16384 * 2;
    ushort* Wb3s = (ushort*)(ws + off); off += 2048 * 2;
    ushort* Wb3n = (ushort*)(ws + off); off += 2048 * 2;

    hipMemsetAsync(gcount, 0, 512 * 4, stream);

    k_front<<<NTB + CASTB + 272, 256, 0, stream>>>(
        src, dst, bins, gcount, x, Xb, W1s, W1n, W2s, W2n, W3s, W3n,
        Wb1s, Wb1n, Wb2s, Wb2n, Wb3s, Wb3n);

    k_bscan<<<1, 256, 0, stream>>>(gcount, ebase);
    k_build<<<NBKT, 256, 0, stream>>>(bins, gcount, ebase, rp, col);

    k_aggemm<<<NNODE / 16, 256, 0, stream>>>(Xb, rp, col, Wb1s, Wb1n, b1, H1);
    k_aggemm<<<NNODE / 16, 256, 0, stream>>>(H1, rp, col, Wb2s, Wb2n, b2, H2);

    k_gemm16d<<<(NNODE + 255) / 256, 256, 0, stream>>>(H2, Wb3n, Wb3s, b3, G3, H3);
    k_agg16<<<(NNODE + 127) / 128, 256, 0, stream>>>(G3, rp, col, H3);

    k_score<<<(EPOS + ENEG + 255) / 256, 256, 0, stream>>>(H3, pos_u, pos_v,
                                                           neg_u, neg_v, out);
}